// Round 1
// baseline (564.721 us; speedup 1.0000x reference)
//
#include <hip/hip_runtime.h>
#include <math.h>

// Problem constants (fixed by setup_inputs):
//   B=8, L=2048, T=512, Dh=1024, Dg=768, Dp=256, SCALE = Dp^-0.5 = 1/16
#define BATCH 8
#define LKEYS 2048
#define TQ    512
#define DH    1024
#define DG    768
#define DP    256
#define SCALE 0.0625f

#define TILE 64
#define BK   16

// ---------------------------------------------------------------------------
// C[M,N] = A[M,K] * B[K,N]   (row-major, batched via blockIdx.z strides)
// block: 16x16 threads, each thread computes a 4x4 micro-tile.
// ---------------------------------------------------------------------------
__global__ __launch_bounds__(256) void gemm_nn_kernel(
    const float* __restrict__ A, const float* __restrict__ B, float* __restrict__ C,
    int M, int N, int K, long sA, long sB, long sC)
{
    A += (long)blockIdx.z * sA;
    B += (long)blockIdx.z * sB;
    C += (long)blockIdx.z * sC;

    __shared__ float As[TILE][BK + 1];  // As[m][kk], +1 pad vs bank conflicts
    __shared__ float Bs[BK][TILE];      // Bs[kk][n]

    const int brow = blockIdx.y * TILE;
    const int bcol = blockIdx.x * TILE;
    const int tx = threadIdx.x, ty = threadIdx.y;
    const int tid = ty * 16 + tx;

    float acc[4][4] = {};

    for (int k0 = 0; k0 < K; k0 += BK) {
        #pragma unroll
        for (int i = 0; i < 4; ++i) {          // 1024 elems / 256 threads
            int idx = tid + i * 256;
            int m = idx >> 4, kk = idx & 15;   // consecutive lanes -> consecutive k (coalesced)
            As[m][kk] = A[(long)(brow + m) * K + (k0 + kk)];
        }
        #pragma unroll
        for (int i = 0; i < 4; ++i) {
            int idx = tid + i * 256;
            int kk = idx >> 6, n = idx & 63;   // consecutive lanes -> consecutive n (coalesced)
            Bs[kk][n] = B[(long)(k0 + kk) * N + (bcol + n)];
        }
        __syncthreads();
        #pragma unroll
        for (int kk = 0; kk < BK; ++kk) {
            float a[4], b[4];
            #pragma unroll
            for (int i = 0; i < 4; ++i) a[i] = As[ty * 4 + i][kk];
            #pragma unroll
            for (int j = 0; j < 4; ++j) b[j] = Bs[kk][tx * 4 + j];
            #pragma unroll
            for (int i = 0; i < 4; ++i)
                #pragma unroll
                for (int j = 0; j < 4; ++j)
                    acc[i][j] = fmaf(a[i], b[j], acc[i][j]);
        }
        __syncthreads();
    }

    #pragma unroll
    for (int i = 0; i < 4; ++i) {
        int r = brow + ty * 4 + i;
        float4 v = make_float4(acc[i][0], acc[i][1], acc[i][2], acc[i][3]);
        *reinterpret_cast<float4*>(&C[(long)r * N + bcol + tx * 4]) = v;
    }
}

// ---------------------------------------------------------------------------
// C[M,N] = scale * A[M,K] * B[N,K]^T, with key-mask epilogue (mask[n] != 0 -> -inf)
// A = Q [T,Dp], B = Kproj [L,Dp], C = logits [T,L]; batched over blockIdx.z.
// ---------------------------------------------------------------------------
__global__ __launch_bounds__(256) void gemm_nt_mask_kernel(
    const float* __restrict__ A, const float* __restrict__ B,
    const int* __restrict__ mask, float* __restrict__ C,
    int M, int N, int K, float scale, long sA, long sB, long sC, long sMask)
{
    A += (long)blockIdx.z * sA;
    B += (long)blockIdx.z * sB;
    C += (long)blockIdx.z * sC;
    mask += (long)blockIdx.z * sMask;

    __shared__ float As[TILE][BK + 1];  // As[m][kk]
    __shared__ float Bs[TILE][BK + 1];  // Bs[n][kk]

    const int brow = blockIdx.y * TILE;
    const int bcol = blockIdx.x * TILE;
    const int tx = threadIdx.x, ty = threadIdx.y;
    const int tid = ty * 16 + tx;

    float acc[4][4] = {};

    for (int k0 = 0; k0 < K; k0 += BK) {
        #pragma unroll
        for (int i = 0; i < 4; ++i) {
            int idx = tid + i * 256;
            int m = idx >> 4, kk = idx & 15;
            As[m][kk] = A[(long)(brow + m) * K + (k0 + kk)];
        }
        #pragma unroll
        for (int i = 0; i < 4; ++i) {
            int idx = tid + i * 256;
            int n = idx >> 4, kk = idx & 15;
            Bs[n][kk] = B[(long)(bcol + n) * K + (k0 + kk)];
        }
        __syncthreads();
        #pragma unroll
        for (int kk = 0; kk < BK; ++kk) {
            float a[4], b[4];
            #pragma unroll
            for (int i = 0; i < 4; ++i) a[i] = As[ty * 4 + i][kk];
            #pragma unroll
            for (int j = 0; j < 4; ++j) b[j] = Bs[tx * 4 + j][kk];
            #pragma unroll
            for (int i = 0; i < 4; ++i)
                #pragma unroll
                for (int j = 0; j < 4; ++j)
                    acc[i][j] = fmaf(a[i], b[j], acc[i][j]);
        }
        __syncthreads();
    }

    #pragma unroll
    for (int i = 0; i < 4; ++i) {
        int r = brow + ty * 4 + i;
        #pragma unroll
        for (int j = 0; j < 4; ++j) {
            int c = bcol + tx * 4 + j;
            float v = (mask[c] != 0) ? -INFINITY : acc[i][j] * scale;
            C[(long)r * N + c] = v;
        }
    }
}

// ---------------------------------------------------------------------------
// In-place row softmax: one 256-thread block per row of length Lr.
// ---------------------------------------------------------------------------
__global__ __launch_bounds__(256) void softmax_rows_kernel(float* __restrict__ S, int Lr)
{
    float* row = S + (long)blockIdx.x * Lr;
    const int tid = threadIdx.x;
    __shared__ float red[4];

    float m = -INFINITY;
    for (int i = tid; i < Lr; i += 256) m = fmaxf(m, row[i]);
    #pragma unroll
    for (int off = 32; off > 0; off >>= 1) m = fmaxf(m, __shfl_xor(m, off));
    if ((tid & 63) == 0) red[tid >> 6] = m;
    __syncthreads();
    m = fmaxf(fmaxf(red[0], red[1]), fmaxf(red[2], red[3]));

    float s = 0.f;
    for (int i = tid; i < Lr; i += 256) {
        float e = __expf(row[i] - m);
        row[i] = e;
        s += e;
    }
    #pragma unroll
    for (int off = 32; off > 0; off >>= 1) s += __shfl_xor(s, off);
    __syncthreads();                      // red[] reuse hazard
    if ((tid & 63) == 0) red[tid >> 6] = s;
    __syncthreads();
    s = red[0] + red[1] + red[2] + red[3];

    float inv = 1.0f / s;
    for (int i = tid; i < Lr; i += 256) row[i] *= inv;
}

// ---------------------------------------------------------------------------
extern "C" void kernel_launch(void* const* d_in, const int* in_sizes, int n_in,
                              void* d_out, int out_size, void* d_ws, size_t ws_size,
                              hipStream_t stream)
{
    const float* H    = (const float*)d_in[0];  // [B,L,Dh]
    const float* G    = (const float*)d_in[1];  // [B,T,Dg]
    const int*   mask = (const int*)  d_in[2];  // [B,L]
    const float* Wk   = (const float*)d_in[3];  // [Dh,Dp]
    const float* Wq   = (const float*)d_in[4];  // [Dg,Dp]
    float*       Z    = (float*)d_out;          // [B,T,Dh]

    // Workspace layout (fp32): K [B,L,Dp] | Q [B,T,Dp] | S [B,T,L]  = 52 MB
    float* Kp = (float*)d_ws;
    float* Qp = Kp + (long)BATCH * LKEYS * DP;   // +16 MB
    float* S  = Qp + (long)BATCH * TQ * DP;      // +4 MB (S is 32 MB)

    dim3 blk(16, 16);

    // 1) K = H @ Wk : M = B*L = 16384, N = 256, K = 1024
    gemm_nn_kernel<<<dim3(DP / TILE, (BATCH * LKEYS) / TILE, 1), blk, 0, stream>>>(
        H, Wk, Kp, BATCH * LKEYS, DP, DH, 0, 0, 0);

    // 2) Q = G @ Wq : M = B*T = 4096, N = 256, K = 768
    gemm_nn_kernel<<<dim3(DP / TILE, (BATCH * TQ) / TILE, 1), blk, 0, stream>>>(
        G, Wq, Qp, BATCH * TQ, DP, DG, 0, 0, 0);

    // 3) logits = scale * Q @ K^T, masked : per batch M=512, N=2048, K=256
    gemm_nt_mask_kernel<<<dim3(LKEYS / TILE, TQ / TILE, BATCH), blk, 0, stream>>>(
        Qp, Kp, mask, S, TQ, LKEYS, DP, SCALE,
        (long)TQ * DP, (long)LKEYS * DP, (long)TQ * LKEYS, (long)LKEYS);

    // 4) softmax over L, in place: B*T = 4096 rows
    softmax_rows_kernel<<<BATCH * TQ, 256, 0, stream>>>(S, LKEYS);

    // 5) Z = alpha @ H : per batch M=512, N=1024, K=2048
    gemm_nn_kernel<<<dim3(DH / TILE, TQ / TILE, BATCH), blk, 0, stream>>>(
        S, H, Z, TQ, DH, LKEYS,
        (long)TQ * LKEYS, (long)LKEYS * DH, (long)TQ * DH);
}

// Round 2
// 223.885 us; speedup vs baseline: 2.5224x; 2.5224x over previous
//
#include <hip/hip_runtime.h>
#include <math.h>

// Problem constants: B=8, L=2048, T=512, Dh=1024, Dg=768, Dp=256, SCALE=Dp^-0.5
#define BATCH 8
#define LKEYS 2048
#define TQ    512
#define DH    1024
#define DG    768
#define DP    256
#define SCALE 0.0625f

typedef short  short8  __attribute__((ext_vector_type(8)));   // 8 bf16 = 4 VGPRs (MFMA A/B frag)
typedef float  floatx4 __attribute__((ext_vector_type(4)));   // MFMA C/D frag
typedef unsigned short u16x4 __attribute__((ext_vector_type(4)));
typedef unsigned short u16x8 __attribute__((ext_vector_type(8)));

__device__ __forceinline__ unsigned short f2b(float f) {
    union { float f; unsigned int u; } v; v.f = f;
    unsigned int u = v.u;
    unsigned int r = u + 0x7fffu + ((u >> 16) & 1u);   // RNE
    if ((u & 0x7f800000u) == 0x7f800000u) r = u;        // inf/nan passthrough
    return (unsigned short)(r >> 16);
}

// ---------------------------------------------------------------------------
// Templated bf16-MFMA GEMM, 128x128 tile, 4 waves (64x64 each), BK=32.
//   AMODE: 0 = A fp32 [M][lda] (convert on stage), 1 = A bf16 [M][lda]
//   BMODE: 0 = B bf16 N-major [N][ldb] (i.e. B^T rows),
//          1 = B fp32 K-major [K][ldb] (transpose+convert on stage)
//   OMODE: 0 = C fp32, 1 = C bf16, 2 = C fp32 with scale + key-mask epilogue
// LDS rows padded to 40 bf16 (80 B): frag ds_read_b128 banks (20r+4g)%32 ->
// full 32-bank coverage per phase, conflict-free.
// ---------------------------------------------------------------------------
#define LDSW 40

template<int AMODE, int BMODE, int OMODE>
__global__ __launch_bounds__(256) void mfma_gemm(
    const void* __restrict__ Ap, const void* __restrict__ Bp,
    const int* __restrict__ maskp, void* __restrict__ Cp,
    int M, int N, int K, int lda, int ldb, int ldc,
    long sA, long sB, long sC, long sM, float scale)
{
    const int z = blockIdx.z;
    __shared__ unsigned short As[128 * LDSW];
    __shared__ unsigned short Bs[128 * LDSW];

    const int tid  = threadIdx.x;
    const int lane = tid & 63;
    const int wid  = tid >> 6;
    const int wr   = wid >> 1, wc = wid & 1;      // 2x2 wave grid
    const int brow = blockIdx.y * 128, bcol = blockIdx.x * 128;
    const int lrow = lane & 15;                    // row/col within 16x16 frag
    const int g    = lane >> 4;                    // k-group (8 bf16 each)

    floatx4 acc[4][4] = {};

    for (int k0 = 0; k0 < K; k0 += 32) {
        // ---- stage A tile [128 x 32] ----
        if (AMODE == 0) {
            const float* A = (const float*)Ap + z * sA;
            #pragma unroll
            for (int i = 0; i < 4; ++i) {
                int e = tid + i * 256;             // 1024 float4 chunks
                int m = e >> 3, c4 = e & 7;
                float4 v = *reinterpret_cast<const float4*>(
                    &A[(long)(brow + m) * lda + k0 + 4 * c4]);
                u16x4 w;
                w[0] = f2b(v.x); w[1] = f2b(v.y); w[2] = f2b(v.z); w[3] = f2b(v.w);
                *reinterpret_cast<u16x4*>(&As[m * LDSW + 4 * c4]) = w;
            }
        } else {
            const unsigned short* A = (const unsigned short*)Ap + z * sA;
            #pragma unroll
            for (int i = 0; i < 2; ++i) {
                int e = tid + i * 256;             // 512 chunks of 8 bf16
                int m = e >> 2, c8 = e & 3;
                u16x8 v = *reinterpret_cast<const u16x8*>(
                    &A[(long)(brow + m) * lda + k0 + 8 * c8]);
                *reinterpret_cast<u16x8*>(&As[m * LDSW + 8 * c8]) = v;
            }
        }
        // ---- stage B tile -> Bs[n][k] ----
        if (BMODE == 0) {
            const unsigned short* B = (const unsigned short*)Bp + z * sB;
            #pragma unroll
            for (int i = 0; i < 2; ++i) {
                int e = tid + i * 256;
                int n = e >> 2, c8 = e & 3;
                u16x8 v = *reinterpret_cast<const u16x8*>(
                    &B[(long)(bcol + n) * ldb + k0 + 8 * c8]);
                *reinterpret_cast<u16x8*>(&Bs[n * LDSW + 8 * c8]) = v;
            }
        } else {
            const float* B = (const float*)Bp + z * sB;
            #pragma unroll
            for (int i = 0; i < 4; ++i) {
                int e = tid + i * 256;             // 1024 float4 chunks
                int kk = e >> 5, c4 = e & 31;
                float4 v = *reinterpret_cast<const float4*>(
                    &B[(long)(k0 + kk) * ldb + bcol + 4 * c4]);
                Bs[(4 * c4 + 0) * LDSW + kk] = f2b(v.x);
                Bs[(4 * c4 + 1) * LDSW + kk] = f2b(v.y);
                Bs[(4 * c4 + 2) * LDSW + kk] = f2b(v.z);
                Bs[(4 * c4 + 3) * LDSW + kk] = f2b(v.w);
            }
        }
        __syncthreads();

        short8 a[4], b[4];
        #pragma unroll
        for (int m = 0; m < 4; ++m)
            a[m] = *reinterpret_cast<const short8*>(
                &As[(wr * 64 + m * 16 + lrow) * LDSW + g * 8]);
        #pragma unroll
        for (int n = 0; n < 4; ++n)
            b[n] = *reinterpret_cast<const short8*>(
                &Bs[(wc * 64 + n * 16 + lrow) * LDSW + g * 8]);
        #pragma unroll
        for (int m = 0; m < 4; ++m)
            #pragma unroll
            for (int n = 0; n < 4; ++n)
                acc[m][n] = __builtin_amdgcn_mfma_f32_16x16x32_bf16(
                    a[m], b[n], acc[m][n], 0, 0, 0);
        __syncthreads();
    }

    // ---- epilogue: D row = 4g + reg, col = lrow (m89-verified layout) ----
    const int orow = brow + wr * 64;
    const int ocol = bcol + wc * 64;
    if (OMODE == 0) {
        float* C = (float*)Cp + z * sC;
        #pragma unroll
        for (int m = 0; m < 4; ++m)
            #pragma unroll
            for (int n = 0; n < 4; ++n)
                #pragma unroll
                for (int r = 0; r < 4; ++r)
                    C[(long)(orow + m * 16 + 4 * g + r) * ldc + ocol + n * 16 + lrow]
                        = acc[m][n][r];
    } else if (OMODE == 1) {
        unsigned short* C = (unsigned short*)Cp + z * sC;
        #pragma unroll
        for (int m = 0; m < 4; ++m)
            #pragma unroll
            for (int n = 0; n < 4; ++n)
                #pragma unroll
                for (int r = 0; r < 4; ++r)
                    C[(long)(orow + m * 16 + 4 * g + r) * ldc + ocol + n * 16 + lrow]
                        = f2b(acc[m][n][r]);
    } else {
        const int* mask = maskp + z * sM;
        float* C = (float*)Cp + z * sC;
        #pragma unroll
        for (int n = 0; n < 4; ++n) {
            int c = ocol + n * 16 + lrow;
            bool masked = (mask[c] != 0);
            #pragma unroll
            for (int m = 0; m < 4; ++m)
                #pragma unroll
                for (int r = 0; r < 4; ++r)
                    C[(long)(orow + m * 16 + 4 * g + r) * ldc + c]
                        = masked ? -INFINITY : acc[m][n][r] * scale;
        }
    }
}

// ---------------------------------------------------------------------------
// Weight transpose + convert: W [D][P] fp32 -> WT [P][D] bf16. 32x32 LDS tile.
// ---------------------------------------------------------------------------
__global__ __launch_bounds__(256) void transpose_w(
    const float* __restrict__ W, unsigned short* __restrict__ WT, int D, int P)
{
    __shared__ float t[32][33];
    const int d0 = blockIdx.x * 32, p0 = blockIdx.y * 32;
    const int tx = threadIdx.x & 31, ty = threadIdx.x >> 5;   // 32x8
    #pragma unroll
    for (int j = 0; j < 4; ++j)
        t[ty + 8 * j][tx] = W[(long)(d0 + ty + 8 * j) * P + p0 + tx];
    __syncthreads();
    #pragma unroll
    for (int j = 0; j < 4; ++j)
        WT[(long)(p0 + ty + 8 * j) * D + d0 + tx] = f2b(t[tx][ty + 8 * j]);
}

// ---------------------------------------------------------------------------
// Row softmax: read fp32 logits S, write bf16 alpha. One block per row.
// ---------------------------------------------------------------------------
__global__ __launch_bounds__(256) void softmax_kernel(
    const float* __restrict__ S, unsigned short* __restrict__ A, int Lr)
{
    const float* row = S + (long)blockIdx.x * Lr;
    unsigned short* arow = A + (long)blockIdx.x * Lr;
    const int tid = threadIdx.x;
    __shared__ float red[4];

    float m = -INFINITY;
    for (int i = tid; i < Lr; i += 256) m = fmaxf(m, row[i]);
    #pragma unroll
    for (int off = 32; off > 0; off >>= 1) m = fmaxf(m, __shfl_xor(m, off));
    if ((tid & 63) == 0) red[tid >> 6] = m;
    __syncthreads();
    m = fmaxf(fmaxf(red[0], red[1]), fmaxf(red[2], red[3]));

    float s = 0.f;
    for (int i = tid; i < Lr; i += 256) s += __expf(row[i] - m);
    #pragma unroll
    for (int off = 32; off > 0; off >>= 1) s += __shfl_xor(s, off);
    __syncthreads();
    if ((tid & 63) == 0) red[tid >> 6] = s;
    __syncthreads();
    s = red[0] + red[1] + red[2] + red[3];

    float inv = 1.0f / s;
    for (int i = tid; i < Lr; i += 256) arow[i] = f2b(__expf(row[i] - m) * inv);
}

// ---------------------------------------------------------------------------
extern "C" void kernel_launch(void* const* d_in, const int* in_sizes, int n_in,
                              void* d_out, int out_size, void* d_ws, size_t ws_size,
                              hipStream_t stream)
{
    const float* H    = (const float*)d_in[0];  // [B,L,Dh]
    const float* G    = (const float*)d_in[1];  // [B,T,Dg]
    const int*   mask = (const int*)  d_in[2];  // [B,L]
    const float* Wk   = (const float*)d_in[3];  // [Dh,Dp]
    const float* Wq   = (const float*)d_in[4];  // [Dg,Dp]
    float*       Z    = (float*)d_out;          // [B,T,Dh]

    // Workspace (bf16 unless noted): WkT | WqT | Kb | Qb | Ab | S(fp32) = 62 MB
    unsigned short* WkT = (unsigned short*)d_ws;              // [Dp][Dh]
    unsigned short* WqT = WkT + (long)DP * DH;                // [Dp][Dg]
    unsigned short* Kb  = WqT + (long)DP * DG;                // [B,L,Dp]
    unsigned short* Qb  = Kb  + (long)BATCH * LKEYS * DP;     // [B,T,Dp]
    unsigned short* Ab  = Qb  + (long)BATCH * TQ * DP;        // [B,T,L]
    float*          S   = (float*)(Ab + (long)BATCH * TQ * LKEYS);  // [B,T,L]

    transpose_w<<<dim3(DH / 32, DP / 32), 256, 0, stream>>>(Wk, WkT, DH, DP);
    transpose_w<<<dim3(DG / 32, DP / 32), 256, 0, stream>>>(Wq, WqT, DG, DP);

    // K = H @ Wk : [16384 x 256 x 1024], out bf16
    mfma_gemm<0, 0, 1><<<dim3(DP / 128, (BATCH * LKEYS) / 128, 1), 256, 0, stream>>>(
        H, WkT, nullptr, Kb, BATCH * LKEYS, DP, DH, DH, DH, DP, 0, 0, 0, 0, 1.f);

    // Q = G @ Wq : [4096 x 256 x 768], out bf16
    mfma_gemm<0, 0, 1><<<dim3(DP / 128, (BATCH * TQ) / 128, 1), 256, 0, stream>>>(
        G, WqT, nullptr, Qb, BATCH * TQ, DP, DG, DG, DG, DP, 0, 0, 0, 0, 1.f);

    // logits = scale * Q @ K^T, masked : per batch [512 x 2048 x 256], out fp32
    mfma_gemm<1, 0, 2><<<dim3(LKEYS / 128, TQ / 128, BATCH), 256, 0, stream>>>(
        Qb, Kb, mask, S, TQ, LKEYS, DP, DP, DP, LKEYS,
        (long)TQ * DP, (long)LKEYS * DP, (long)TQ * LKEYS, (long)LKEYS, SCALE);

    // softmax over L -> bf16 alpha
    softmax_kernel<<<BATCH * TQ, 256, 0, stream>>>(S, Ab, LKEYS);

    // Z = alpha @ H : per batch [512 x 1024 x 2048], B fp32 K-major, out fp32
    mfma_gemm<1, 1, 0><<<dim3(DH / 128, TQ / 128, BATCH), 256, 0, stream>>>(
        Ab, H, nullptr, Z, TQ, DH, LKEYS, LKEYS, DH, DH,
        (long)TQ * LKEYS, (long)LKEYS * DH, (long)TQ * DH, 0, 1.f);
}

// Round 3
// 157.354 us; speedup vs baseline: 3.5889x; 1.4228x over previous
//
#include <hip/hip_runtime.h>
#include <math.h>

// Problem constants: B=8, L=2048, T=512, Dh=1024, Dg=768, Dp=256, SCALE=Dp^-0.5
#define BATCH 8
#define LKEYS 2048
#define TQ    512
#define DH    1024
#define DG    768
#define DP    256
#define SCALE 0.0625f

typedef short  short8  __attribute__((ext_vector_type(8)));   // MFMA A/B frag (8 bf16)
typedef float  floatx4 __attribute__((ext_vector_type(4)));   // MFMA C/D frag
typedef unsigned short u16x4 __attribute__((ext_vector_type(4)));
typedef unsigned short u16x8 __attribute__((ext_vector_type(8)));

typedef unsigned int __attribute__((address_space(1))) as1_uint;
typedef unsigned int __attribute__((address_space(3))) as3_uint;

__device__ __forceinline__ unsigned short f2b(float f) {
    union { float f; unsigned int u; } v; v.f = f;
    unsigned int u = v.u;
    unsigned int r = u + 0x7fffu + ((u >> 16) & 1u);   // RNE
    if ((u & 0x7f800000u) == 0x7f800000u) r = u;        // inf/nan passthrough
    return (unsigned short)(r >> 16);
}

// async global->LDS, 16B per lane. LDS dest is lane-linear (wave-uniform base + lane*16).
__device__ __forceinline__ void gload_lds16(const void* g, void* l) {
    __builtin_amdgcn_global_load_lds((const as1_uint*)g, (as3_uint*)l, 16, 0, 0);
}

// ---------------------------------------------------------------------------
// bf16-MFMA GEMM, m97 structure: 128x128 tile, 4 waves (2x2, 64x64 each),
// BK=32, linear [128][32] bf16 LDS (64B rows -> frag ds_read_b128 hits the
// b128 bank floor, no swizzle needed), double-buffered, global_load_lds
// staging for bf16 operands, reg-staged convert for fp32 A.
//   AMODE: 0 = A fp32 row-major, 1 = A bf16 row-major
//   OMODE: 0 = C fp32, 1 = C bf16, 2 = C fp32 with scale + key-mask epilogue
// B is always bf16 N-major (row n holds B^T[n][k]).
// ---------------------------------------------------------------------------
template<int AMODE, int OMODE>
__global__ __launch_bounds__(256) void mfma_gemm(
    const void* __restrict__ Ap, const unsigned short* __restrict__ Bp,
    const int* __restrict__ maskp, void* __restrict__ Cp,
    int K, int lda, int ldb, int ldc,
    long sA, long sB, long sC, long sM, float scale)
{
    __shared__ unsigned short As[2][128 * 32];
    __shared__ unsigned short Bs[2][128 * 32];

    const int z    = blockIdx.z;
    const int tid  = threadIdx.x;
    const int lane = tid & 63;
    const int wid  = tid >> 6;
    const int wr   = wid >> 1, wc = wid & 1;     // 2x2 wave grid
    const int lrow = lane & 15;
    const int g    = lane >> 4;

    const unsigned short* B = Bp + (long)z * sB + (long)(blockIdx.x * 128) * ldb;

    // staging geometry: chunk s = i*256+tid in [0,1024) -> row = s>>2, slot = s&3
    const int srow = tid >> 2, sslot = tid & 3;

    floatx4 acc[4][4] = {};
    const int nt = K / 32;
    int cur = 0;

    if (AMODE == 1) {
        const unsigned short* A = (const unsigned short*)Ap + (long)z * sA
                                + (long)(blockIdx.y * 128) * lda;
        // prologue: stage tile 0
        #pragma unroll
        for (int i = 0; i < 2; ++i) {
            int s = i * 256 + tid, row = srow + i * 64;
            gload_lds16(A + (long)row * lda + sslot * 8, (void*)&As[0][s * 8]);
            gload_lds16(B + (long)row * ldb + sslot * 8, (void*)&Bs[0][s * 8]);
        }
        __syncthreads();

        for (int t = 0; t < nt; ++t) {
            if (t + 1 < nt) {
                int k0 = (t + 1) * 32;
                #pragma unroll
                for (int i = 0; i < 2; ++i) {
                    int s = i * 256 + tid, row = srow + i * 64;
                    gload_lds16(A + (long)row * lda + k0 + sslot * 8, (void*)&As[cur ^ 1][s * 8]);
                    gload_lds16(B + (long)row * ldb + k0 + sslot * 8, (void*)&Bs[cur ^ 1][s * 8]);
                }
            }
            short8 a[4], b[4];
            #pragma unroll
            for (int m = 0; m < 4; ++m)
                a[m] = *(const short8*)&As[cur][(wr * 64 + m * 16 + lrow) * 32 + g * 8];
            #pragma unroll
            for (int n = 0; n < 4; ++n)
                b[n] = *(const short8*)&Bs[cur][(wc * 64 + n * 16 + lrow) * 32 + g * 8];
            #pragma unroll
            for (int m = 0; m < 4; ++m)
                #pragma unroll
                for (int n = 0; n < 4; ++n)
                    acc[m][n] = __builtin_amdgcn_mfma_f32_16x16x32_bf16(
                        a[m], b[n], acc[m][n], 0, 0, 0);
            __syncthreads();
            cur ^= 1;
        }
    } else {
        const float* A = (const float*)Ap + (long)z * sA + (long)(blockIdx.y * 128) * lda;
        // prologue: reg-load A tile 0, gload B tile 0, convert+write, sync
        {
            float4 pa[2][2];
            #pragma unroll
            for (int i = 0; i < 2; ++i) {
                int row = srow + i * 64;
                const float* p = A + (long)row * lda + sslot * 8;
                pa[i][0] = *(const float4*)p;
                pa[i][1] = *(const float4*)(p + 4);
                gload_lds16(B + (long)row * ldb + sslot * 8, (void*)&Bs[0][(i * 256 + tid) * 8]);
            }
            #pragma unroll
            for (int i = 0; i < 2; ++i) {
                u16x8 w;
                w[0] = f2b(pa[i][0].x); w[1] = f2b(pa[i][0].y);
                w[2] = f2b(pa[i][0].z); w[3] = f2b(pa[i][0].w);
                w[4] = f2b(pa[i][1].x); w[5] = f2b(pa[i][1].y);
                w[6] = f2b(pa[i][1].z); w[7] = f2b(pa[i][1].w);
                *(u16x8*)&As[0][(i * 256 + tid) * 8] = w;
            }
        }
        __syncthreads();

        for (int t = 0; t < nt; ++t) {
            float4 pa[2][2];
            const bool pf = (t + 1 < nt);
            if (pf) {
                int k0 = (t + 1) * 32;
                #pragma unroll
                for (int i = 0; i < 2; ++i) {
                    int row = srow + i * 64;
                    const float* p = A + (long)row * lda + k0 + sslot * 8;
                    pa[i][0] = *(const float4*)p;
                    pa[i][1] = *(const float4*)(p + 4);
                    gload_lds16(B + (long)row * ldb + k0 + sslot * 8,
                                (void*)&Bs[cur ^ 1][(i * 256 + tid) * 8]);
                }
            }
            short8 a[4], b[4];
            #pragma unroll
            for (int m = 0; m < 4; ++m)
                a[m] = *(const short8*)&As[cur][(wr * 64 + m * 16 + lrow) * 32 + g * 8];
            #pragma unroll
            for (int n = 0; n < 4; ++n)
                b[n] = *(const short8*)&Bs[cur][(wc * 64 + n * 16 + lrow) * 32 + g * 8];
            #pragma unroll
            for (int m = 0; m < 4; ++m)
                #pragma unroll
                for (int n = 0; n < 4; ++n)
                    acc[m][n] = __builtin_amdgcn_mfma_f32_16x16x32_bf16(
                        a[m], b[n], acc[m][n], 0, 0, 0);
            if (pf) {
                #pragma unroll
                for (int i = 0; i < 2; ++i) {
                    u16x8 w;
                    w[0] = f2b(pa[i][0].x); w[1] = f2b(pa[i][0].y);
                    w[2] = f2b(pa[i][0].z); w[3] = f2b(pa[i][0].w);
                    w[4] = f2b(pa[i][1].x); w[5] = f2b(pa[i][1].y);
                    w[6] = f2b(pa[i][1].z); w[7] = f2b(pa[i][1].w);
                    *(u16x8*)&As[cur ^ 1][(i * 256 + tid) * 8] = w;
                }
            }
            __syncthreads();
            cur ^= 1;
        }
    }

    // ---- epilogue: D row = 4g + reg, col = lrow (m89-verified layout) ----
    const int orow = blockIdx.y * 128 + wr * 64;
    const int ocol = blockIdx.x * 128 + wc * 64;
    if (OMODE == 0) {
        float* C = (float*)Cp + (long)z * sC;
        #pragma unroll
        for (int m = 0; m < 4; ++m)
            #pragma unroll
            for (int n = 0; n < 4; ++n)
                #pragma unroll
                for (int r = 0; r < 4; ++r)
                    C[(long)(orow + m * 16 + 4 * g + r) * ldc + ocol + n * 16 + lrow]
                        = acc[m][n][r];
    } else if (OMODE == 1) {
        unsigned short* C = (unsigned short*)Cp + (long)z * sC;
        #pragma unroll
        for (int m = 0; m < 4; ++m)
            #pragma unroll
            for (int n = 0; n < 4; ++n)
                #pragma unroll
                for (int r = 0; r < 4; ++r)
                    C[(long)(orow + m * 16 + 4 * g + r) * ldc + ocol + n * 16 + lrow]
                        = f2b(acc[m][n][r]);
    } else {
        const int* mask = maskp + (long)z * sM;
        float* C = (float*)Cp + (long)z * sC;
        #pragma unroll
        for (int n = 0; n < 4; ++n) {
            int c = ocol + n * 16 + lrow;
            bool masked = (mask[c] != 0);
            #pragma unroll
            for (int m = 0; m < 4; ++m)
                #pragma unroll
                for (int r = 0; r < 4; ++r)
                    C[(long)(orow + m * 16 + 4 * g + r) * ldc + c]
                        = masked ? -INFINITY : acc[m][n][r] * scale;
        }
    }
}

// ---------------------------------------------------------------------------
// Weight transpose + convert: W [D][P] fp32 -> WT [P][D] bf16.
// ---------------------------------------------------------------------------
__global__ __launch_bounds__(256) void transpose_w(
    const float* __restrict__ W, unsigned short* __restrict__ WT, int D, int P)
{
    __shared__ float t[32][33];
    const int d0 = blockIdx.x * 32, p0 = blockIdx.y * 32;
    const int tx = threadIdx.x & 31, ty = threadIdx.x >> 5;   // 32x8
    #pragma unroll
    for (int j = 0; j < 4; ++j)
        t[ty + 8 * j][tx] = W[(long)(d0 + ty + 8 * j) * P + p0 + tx];
    __syncthreads();
    #pragma unroll
    for (int j = 0; j < 4; ++j)
        WT[(long)(p0 + ty + 8 * j) * D + d0 + tx] = f2b(t[tx][ty + 8 * j]);
}

// ---------------------------------------------------------------------------
// H [B,L,Dh] fp32 -> HbT [B,Dh,L] bf16 (transpose per batch, 32x32 tiles).
// ---------------------------------------------------------------------------
__global__ __launch_bounds__(256) void prep_HT(
    const float* __restrict__ H, unsigned short* __restrict__ HbT)
{
    __shared__ float tf[32][33];
    const int z = blockIdx.z;
    const int d0 = blockIdx.x * 32, l0 = blockIdx.y * 32;
    const float* Hz = H + (long)z * LKEYS * DH;
    unsigned short* Tz = HbT + (long)z * DH * LKEYS;
    const int r = threadIdx.x >> 3, c = threadIdx.x & 7;
    float4 v = *(const float4*)&Hz[(long)(l0 + r) * DH + d0 + 4 * c];
    tf[r][4 * c + 0] = v.x; tf[r][4 * c + 1] = v.y;
    tf[r][4 * c + 2] = v.z; tf[r][4 * c + 3] = v.w;
    __syncthreads();
    u16x4 o;
    o[0] = f2b(tf[4 * c + 0][r]); o[1] = f2b(tf[4 * c + 1][r]);
    o[2] = f2b(tf[4 * c + 2][r]); o[3] = f2b(tf[4 * c + 3][r]);
    *(u16x4*)&Tz[(long)(d0 + r) * LKEYS + l0 + 4 * c] = o;
}

// ---------------------------------------------------------------------------
// Row softmax, register-cached: 2048 floats/row, 256 threads, 8 elems/thread.
// Reads fp32 logits, writes bf16 alpha.
// ---------------------------------------------------------------------------
__global__ __launch_bounds__(256) void softmax_kernel(
    const float* __restrict__ S, unsigned short* __restrict__ Ab)
{
    const float4* row4 = (const float4*)(S + (long)blockIdx.x * LKEYS);
    u16x4* out4 = (u16x4*)(Ab + (long)blockIdx.x * LKEYS);
    const int tid = threadIdx.x;
    __shared__ float red[4];

    float4 v0 = row4[tid], v1 = row4[tid + 256];
    float m = fmaxf(fmaxf(fmaxf(v0.x, v0.y), fmaxf(v0.z, v0.w)),
                    fmaxf(fmaxf(v1.x, v1.y), fmaxf(v1.z, v1.w)));
    #pragma unroll
    for (int off = 32; off > 0; off >>= 1) m = fmaxf(m, __shfl_xor(m, off));
    if ((tid & 63) == 0) red[tid >> 6] = m;
    __syncthreads();
    m = fmaxf(fmaxf(red[0], red[1]), fmaxf(red[2], red[3]));

    float e[8];
    e[0] = __expf(v0.x - m); e[1] = __expf(v0.y - m);
    e[2] = __expf(v0.z - m); e[3] = __expf(v0.w - m);
    e[4] = __expf(v1.x - m); e[5] = __expf(v1.y - m);
    e[6] = __expf(v1.z - m); e[7] = __expf(v1.w - m);
    float s = ((e[0] + e[1]) + (e[2] + e[3])) + ((e[4] + e[5]) + (e[6] + e[7]));
    #pragma unroll
    for (int off = 32; off > 0; off >>= 1) s += __shfl_xor(s, off);
    __syncthreads();
    if ((tid & 63) == 0) red[tid >> 6] = s;
    __syncthreads();
    s = red[0] + red[1] + red[2] + red[3];

    float inv = 1.0f / s;
    u16x4 a0, a1;
    a0[0] = f2b(e[0] * inv); a0[1] = f2b(e[1] * inv);
    a0[2] = f2b(e[2] * inv); a0[3] = f2b(e[3] * inv);
    a1[0] = f2b(e[4] * inv); a1[1] = f2b(e[5] * inv);
    a1[2] = f2b(e[6] * inv); a1[3] = f2b(e[7] * inv);
    out4[tid] = a0; out4[tid + 256] = a1;
}

// ---------------------------------------------------------------------------
extern "C" void kernel_launch(void* const* d_in, const int* in_sizes, int n_in,
                              void* d_out, int out_size, void* d_ws, size_t ws_size,
                              hipStream_t stream)
{
    const float* H    = (const float*)d_in[0];  // [B,L,Dh]
    const float* G    = (const float*)d_in[1];  // [B,T,Dg]
    const int*   mask = (const int*)  d_in[2];  // [B,L]
    const float* Wk   = (const float*)d_in[3];  // [Dh,Dp]
    const float* Wq   = (const float*)d_in[4];  // [Dg,Dp]
    float*       Z    = (float*)d_out;          // [B,T,Dh]

    // ws (61.7 MB): WkT | WqT | Ab | region[ Kb | Qb | S ], HbT overlays region
    unsigned short* WkT = (unsigned short*)d_ws;               // 256*1024
    unsigned short* WqT = WkT + (long)DP * DH;                 // 256*768
    unsigned short* Ab  = WqT + (long)DP * DG;                 // 8*512*2048
    unsigned short* R   = Ab  + (long)BATCH * TQ * LKEYS;
    unsigned short* Kb  = R;                                   // 8*2048*256
    unsigned short* Qb  = Kb + (long)BATCH * LKEYS * DP;       // 8*512*256
    float*          S   = (float*)(Qb + (long)BATCH * TQ * DP);// 8*512*2048 f32
    unsigned short* HbT = R;   // [B,Dh,L] bf16, written after S is dead

    transpose_w<<<dim3(DH / 32, DP / 32), 256, 0, stream>>>(Wk, WkT, DH, DP);
    transpose_w<<<dim3(DG / 32, DP / 32), 256, 0, stream>>>(Wq, WqT, DG, DP);

    // K = H @ Wk : M=16384, N=256, K=1024 (A fp32, out bf16)
    mfma_gemm<0, 1><<<dim3(DP / 128, (BATCH * LKEYS) / 128, 1), 256, 0, stream>>>(
        H, WkT, nullptr, Kb, DH, DH, DH, DP, 0, 0, 0, 0, 1.f);

    // Q = G @ Wq : M=4096, N=256, K=768 (A fp32, out bf16)
    mfma_gemm<0, 1><<<dim3(DP / 128, (BATCH * TQ) / 128, 1), 256, 0, stream>>>(
        G, WqT, nullptr, Qb, DG, DG, DG, DP, 0, 0, 0, 0, 1.f);

    // logits = scale * Q @ K^T, masked : per batch M=512, N=2048, K=256 (out fp32)
    mfma_gemm<1, 2><<<dim3(LKEYS / 128, TQ / 128, BATCH), 256, 0, stream>>>(
        Qb, Kb, mask, S, DP, DP, DP, LKEYS,
        (long)TQ * DP, (long)LKEYS * DP, (long)TQ * LKEYS, (long)LKEYS, SCALE);

    // softmax over L -> bf16 alpha
    softmax_kernel<<<BATCH * TQ, 256, 0, stream>>>(S, Ab);

    // H^T prep (S/Kb/Qb now dead; HbT overlays them)
    prep_HT<<<dim3(DH / 32, LKEYS / 32, BATCH), 256, 0, stream>>>(H, HbT);

    // Z = alpha @ H : per batch M=512, N=1024, K=2048 (out fp32)
    mfma_gemm<1, 0><<<dim3(DH / 128, TQ / 128, BATCH), 256, 0, stream>>>(
        Ab, HbT, nullptr, Z, LKEYS, LKEYS, LKEYS, DH,
        (long)TQ * LKEYS, (long)DH * LKEYS, (long)TQ * DH, 0, 1.f);
}

// Round 4
// 152.627 us; speedup vs baseline: 3.7000x; 1.0310x over previous
//
#include <hip/hip_runtime.h>
#include <math.h>

// Problem constants: B=8, L=2048, T=512, Dh=1024, Dg=768, Dp=256, SCALE=Dp^-0.5
#define BATCH 8
#define LKEYS 2048
#define TQ    512
#define DH    1024
#define DG    768
#define DP    256
#define SCALE 0.0625f

typedef short  short8  __attribute__((ext_vector_type(8)));   // MFMA A/B frag (8 bf16)
typedef float  floatx4 __attribute__((ext_vector_type(4)));   // MFMA C/D frag
typedef unsigned short u16x4 __attribute__((ext_vector_type(4)));
typedef unsigned short u16x8 __attribute__((ext_vector_type(8)));

typedef unsigned int __attribute__((address_space(1))) as1_uint;
typedef unsigned int __attribute__((address_space(3))) as3_uint;

__device__ __forceinline__ unsigned short f2b(float f) {
    union { float f; unsigned int u; } v; v.f = f;
    unsigned int u = v.u;
    unsigned int r = u + 0x7fffu + ((u >> 16) & 1u);   // RNE
    if ((u & 0x7f800000u) == 0x7f800000u) r = u;        // inf/nan passthrough
    return (unsigned short)(r >> 16);
}

// async global->LDS, 16B per lane (lane-linear LDS dest).
__device__ __forceinline__ void gload_lds16(const void* g, void* l) {
    __builtin_amdgcn_global_load_lds((const as1_uint*)g, (as3_uint*)l, 16, 0, 0);
}

// ---------------------------------------------------------------------------
// bf16-MFMA GEMM, m97 structure, templated tile BM x BN (multiples of 64),
// 4 waves in a 2x2 grid, each computing (BM/2)x(BN/2) via 16x16x32 MFMA.
// BK=32, linear [rows][32] bf16 LDS (64B rows), double-buffered.
//   AMODE: 0 = A fp32 row-major (reg-stage + convert), 1 = A bf16 (gload_lds)
//   OMODE: 0 = C fp32, 1 = C bf16, 2 = C fp32 with scale + key-mask epilogue
// B is always bf16 N-major (row n holds B^T[n][k]), staged via gload_lds.
// Occupancy note: BN=64 halves the tile so the skinny-N GEMMs here launch
// >=512 blocks (>=2 waves/SIMD) instead of 256 (1/SIMD, 84% idle in R3).
// ---------------------------------------------------------------------------
template<int BM, int BN, int AMODE, int OMODE>
__global__ __launch_bounds__(256) void mfma_gemm(
    const void* __restrict__ Ap, const unsigned short* __restrict__ Bp,
    const int* __restrict__ maskp, void* __restrict__ Cp,
    int K, int lda, int ldb, int ldc,
    long sA, long sB, long sC, long sM, float scale)
{
    constexpr int FM = BM / 32;       // m-frags per wave
    constexpr int FN = BN / 32;       // n-frags per wave
    constexpr int AI = BM / 64;       // 256-thread staging iters for A
    constexpr int BI = BN / 64;       // 256-thread staging iters for B

    __shared__ unsigned short As[2][BM * 32];
    __shared__ unsigned short Bs[2][BN * 32];

    const int z    = blockIdx.z;
    const int tid  = threadIdx.x;
    const int lane = tid & 63;
    const int wid  = tid >> 6;
    const int wr   = wid >> 1, wc = wid & 1;     // 2x2 wave grid
    const int lrow = lane & 15;
    const int g    = lane >> 4;

    const unsigned short* B = Bp + (long)z * sB + (long)(blockIdx.x * BN) * ldb;

    // staging geometry: chunk s = i*256+tid -> row = s>>2, 16B slot = s&3
    const int srow = tid >> 2, sslot = tid & 3;

    floatx4 acc[FM][FN] = {};
    const int nt = K / 32;
    int cur = 0;

    if (AMODE == 1) {
        const unsigned short* A = (const unsigned short*)Ap + (long)z * sA
                                + (long)(blockIdx.y * BM) * lda;
        #pragma unroll
        for (int i = 0; i < AI; ++i)
            gload_lds16(A + (long)(srow + i * 64) * lda + sslot * 8,
                        (void*)&As[0][(i * 256 + tid) * 8]);
        #pragma unroll
        for (int i = 0; i < BI; ++i)
            gload_lds16(B + (long)(srow + i * 64) * ldb + sslot * 8,
                        (void*)&Bs[0][(i * 256 + tid) * 8]);
        __syncthreads();

        for (int t = 0; t < nt; ++t) {
            if (t + 1 < nt) {
                int k0 = (t + 1) * 32;
                #pragma unroll
                for (int i = 0; i < AI; ++i)
                    gload_lds16(A + (long)(srow + i * 64) * lda + k0 + sslot * 8,
                                (void*)&As[cur ^ 1][(i * 256 + tid) * 8]);
                #pragma unroll
                for (int i = 0; i < BI; ++i)
                    gload_lds16(B + (long)(srow + i * 64) * ldb + k0 + sslot * 8,
                                (void*)&Bs[cur ^ 1][(i * 256 + tid) * 8]);
            }
            short8 a[FM], b[FN];
            #pragma unroll
            for (int m = 0; m < FM; ++m)
                a[m] = *(const short8*)&As[cur][(wr * (BM / 2) + m * 16 + lrow) * 32 + g * 8];
            #pragma unroll
            for (int n = 0; n < FN; ++n)
                b[n] = *(const short8*)&Bs[cur][(wc * (BN / 2) + n * 16 + lrow) * 32 + g * 8];
            #pragma unroll
            for (int m = 0; m < FM; ++m)
                #pragma unroll
                for (int n = 0; n < FN; ++n)
                    acc[m][n] = __builtin_amdgcn_mfma_f32_16x16x32_bf16(
                        a[m], b[n], acc[m][n], 0, 0, 0);
            __syncthreads();
            cur ^= 1;
        }
    } else {
        const float* A = (const float*)Ap + (long)z * sA + (long)(blockIdx.y * BM) * lda;
        {
            float4 pa[AI][2];
            #pragma unroll
            for (int i = 0; i < AI; ++i) {
                const float* p = A + (long)(srow + i * 64) * lda + sslot * 8;
                pa[i][0] = *(const float4*)p;
                pa[i][1] = *(const float4*)(p + 4);
            }
            #pragma unroll
            for (int i = 0; i < BI; ++i)
                gload_lds16(B + (long)(srow + i * 64) * ldb + sslot * 8,
                            (void*)&Bs[0][(i * 256 + tid) * 8]);
            #pragma unroll
            for (int i = 0; i < AI; ++i) {
                u16x8 w;
                w[0] = f2b(pa[i][0].x); w[1] = f2b(pa[i][0].y);
                w[2] = f2b(pa[i][0].z); w[3] = f2b(pa[i][0].w);
                w[4] = f2b(pa[i][1].x); w[5] = f2b(pa[i][1].y);
                w[6] = f2b(pa[i][1].z); w[7] = f2b(pa[i][1].w);
                *(u16x8*)&As[0][(i * 256 + tid) * 8] = w;
            }
        }
        __syncthreads();

        for (int t = 0; t < nt; ++t) {
            float4 pa[AI][2];
            const bool pf = (t + 1 < nt);
            if (pf) {
                int k0 = (t + 1) * 32;
                #pragma unroll
                for (int i = 0; i < AI; ++i) {
                    const float* p = A + (long)(srow + i * 64) * lda + k0 + sslot * 8;
                    pa[i][0] = *(const float4*)p;
                    pa[i][1] = *(const float4*)(p + 4);
                }
                #pragma unroll
                for (int i = 0; i < BI; ++i)
                    gload_lds16(B + (long)(srow + i * 64) * ldb + k0 + sslot * 8,
                                (void*)&Bs[cur ^ 1][(i * 256 + tid) * 8]);
            }
            short8 a[FM], b[FN];
            #pragma unroll
            for (int m = 0; m < FM; ++m)
                a[m] = *(const short8*)&As[cur][(wr * (BM / 2) + m * 16 + lrow) * 32 + g * 8];
            #pragma unroll
            for (int n = 0; n < FN; ++n)
                b[n] = *(const short8*)&Bs[cur][(wc * (BN / 2) + n * 16 + lrow) * 32 + g * 8];
            #pragma unroll
            for (int m = 0; m < FM; ++m)
                #pragma unroll
                for (int n = 0; n < FN; ++n)
                    acc[m][n] = __builtin_amdgcn_mfma_f32_16x16x32_bf16(
                        a[m], b[n], acc[m][n], 0, 0, 0);
            if (pf) {
                #pragma unroll
                for (int i = 0; i < AI; ++i) {
                    u16x8 w;
                    w[0] = f2b(pa[i][0].x); w[1] = f2b(pa[i][0].y);
                    w[2] = f2b(pa[i][0].z); w[3] = f2b(pa[i][0].w);
                    w[4] = f2b(pa[i][1].x); w[5] = f2b(pa[i][1].y);
                    w[6] = f2b(pa[i][1].z); w[7] = f2b(pa[i][1].w);
                    *(u16x8*)&As[cur ^ 1][(i * 256 + tid) * 8] = w;
                }
            }
            __syncthreads();
            cur ^= 1;
        }
    }

    // ---- epilogue: D row = 4g + reg, col = lrow (m89-verified layout) ----
    const int orow = blockIdx.y * BM + wr * (BM / 2);
    const int ocol = blockIdx.x * BN + wc * (BN / 2);
    if (OMODE == 0) {
        float* C = (float*)Cp + (long)z * sC;
        #pragma unroll
        for (int m = 0; m < FM; ++m)
            #pragma unroll
            for (int n = 0; n < FN; ++n)
                #pragma unroll
                for (int r = 0; r < 4; ++r)
                    C[(long)(orow + m * 16 + 4 * g + r) * ldc + ocol + n * 16 + lrow]
                        = acc[m][n][r];
    } else if (OMODE == 1) {
        unsigned short* C = (unsigned short*)Cp + (long)z * sC;
        #pragma unroll
        for (int m = 0; m < FM; ++m)
            #pragma unroll
            for (int n = 0; n < FN; ++n)
                #pragma unroll
                for (int r = 0; r < 4; ++r)
                    C[(long)(orow + m * 16 + 4 * g + r) * ldc + ocol + n * 16 + lrow]
                        = f2b(acc[m][n][r]);
    } else {
        const int* mask = maskp + (long)z * sM;
        float* C = (float*)Cp + (long)z * sC;
        #pragma unroll
        for (int n = 0; n < FN; ++n) {
            int c = ocol + n * 16 + lrow;
            bool masked = (mask[c] != 0);
            #pragma unroll
            for (int m = 0; m < FM; ++m)
                #pragma unroll
                for (int r = 0; r < 4; ++r)
                    C[(long)(orow + m * 16 + 4 * g + r) * ldc + c]
                        = masked ? -INFINITY : acc[m][n][r] * scale;
        }
    }
}

// ---------------------------------------------------------------------------
// Weight transpose + convert: W [D][P] fp32 -> WT [P][D] bf16.
// ---------------------------------------------------------------------------
__global__ __launch_bounds__(256) void transpose_w(
    const float* __restrict__ W, unsigned short* __restrict__ WT, int D, int P)
{
    __shared__ float t[32][33];
    const int d0 = blockIdx.x * 32, p0 = blockIdx.y * 32;
    const int tx = threadIdx.x & 31, ty = threadIdx.x >> 5;   // 32x8
    #pragma unroll
    for (int j = 0; j < 4; ++j)
        t[ty + 8 * j][tx] = W[(long)(d0 + ty + 8 * j) * P + p0 + tx];
    __syncthreads();
    #pragma unroll
    for (int j = 0; j < 4; ++j)
        WT[(long)(p0 + ty + 8 * j) * D + d0 + tx] = f2b(t[tx][ty + 8 * j]);
}

// ---------------------------------------------------------------------------
// H [B,L,Dh] fp32 -> HbT [B,Dh,L] bf16 (transpose per batch, 32x32 tiles).
// ---------------------------------------------------------------------------
__global__ __launch_bounds__(256) void prep_HT(
    const float* __restrict__ H, unsigned short* __restrict__ HbT)
{
    __shared__ float tf[32][33];
    const int z = blockIdx.z;
    const int d0 = blockIdx.x * 32, l0 = blockIdx.y * 32;
    const float* Hz = H + (long)z * LKEYS * DH;
    unsigned short* Tz = HbT + (long)z * DH * LKEYS;
    const int r = threadIdx.x >> 3, c = threadIdx.x & 7;
    float4 v = *(const float4*)&Hz[(long)(l0 + r) * DH + d0 + 4 * c];
    tf[r][4 * c + 0] = v.x; tf[r][4 * c + 1] = v.y;
    tf[r][4 * c + 2] = v.z; tf[r][4 * c + 3] = v.w;
    __syncthreads();
    u16x4 o;
    o[0] = f2b(tf[4 * c + 0][r]); o[1] = f2b(tf[4 * c + 1][r]);
    o[2] = f2b(tf[4 * c + 2][r]); o[3] = f2b(tf[4 * c + 3][r]);
    *(u16x4*)&Tz[(long)(d0 + r) * LKEYS + l0 + 4 * c] = o;
}

// ---------------------------------------------------------------------------
// Row softmax, register-cached: 2048 floats/row, 256 threads, 8 elems/thread.
// ---------------------------------------------------------------------------
__global__ __launch_bounds__(256) void softmax_kernel(
    const float* __restrict__ S, unsigned short* __restrict__ Ab)
{
    const float4* row4 = (const float4*)(S + (long)blockIdx.x * LKEYS);
    u16x4* out4 = (u16x4*)(Ab + (long)blockIdx.x * LKEYS);
    const int tid = threadIdx.x;
    __shared__ float red[4];

    float4 v0 = row4[tid], v1 = row4[tid + 256];
    float m = fmaxf(fmaxf(fmaxf(v0.x, v0.y), fmaxf(v0.z, v0.w)),
                    fmaxf(fmaxf(v1.x, v1.y), fmaxf(v1.z, v1.w)));
    #pragma unroll
    for (int off = 32; off > 0; off >>= 1) m = fmaxf(m, __shfl_xor(m, off));
    if ((tid & 63) == 0) red[tid >> 6] = m;
    __syncthreads();
    m = fmaxf(fmaxf(red[0], red[1]), fmaxf(red[2], red[3]));

    float e[8];
    e[0] = __expf(v0.x - m); e[1] = __expf(v0.y - m);
    e[2] = __expf(v0.z - m); e[3] = __expf(v0.w - m);
    e[4] = __expf(v1.x - m); e[5] = __expf(v1.y - m);
    e[6] = __expf(v1.z - m); e[7] = __expf(v1.w - m);
    float s = ((e[0] + e[1]) + (e[2] + e[3])) + ((e[4] + e[5]) + (e[6] + e[7]));
    #pragma unroll
    for (int off = 32; off > 0; off >>= 1) s += __shfl_xor(s, off);
    __syncthreads();
    if ((tid & 63) == 0) red[tid >> 6] = s;
    __syncthreads();
    s = red[0] + red[1] + red[2] + red[3];

    float inv = 1.0f / s;
    u16x4 a0, a1;
    a0[0] = f2b(e[0] * inv); a0[1] = f2b(e[1] * inv);
    a0[2] = f2b(e[2] * inv); a0[3] = f2b(e[3] * inv);
    a1[0] = f2b(e[4] * inv); a1[1] = f2b(e[5] * inv);
    a1[2] = f2b(e[6] * inv); a1[3] = f2b(e[7] * inv);
    out4[tid] = a0; out4[tid + 256] = a1;
}

// ---------------------------------------------------------------------------
extern "C" void kernel_launch(void* const* d_in, const int* in_sizes, int n_in,
                              void* d_out, int out_size, void* d_ws, size_t ws_size,
                              hipStream_t stream)
{
    const float* H    = (const float*)d_in[0];  // [B,L,Dh]
    const float* G    = (const float*)d_in[1];  // [B,T,Dg]
    const int*   mask = (const int*)  d_in[2];  // [B,L]
    const float* Wk   = (const float*)d_in[3];  // [Dh,Dp]
    const float* Wq   = (const float*)d_in[4];  // [Dg,Dp]
    float*       Z    = (float*)d_out;          // [B,T,Dh]

    // ws (61.7 MB): WkT | WqT | Ab | region[ Kb | Qb | S ], HbT overlays region
    unsigned short* WkT = (unsigned short*)d_ws;               // 256*1024
    unsigned short* WqT = WkT + (long)DP * DH;                 // 256*768
    unsigned short* Ab  = WqT + (long)DP * DG;                 // 8*512*2048
    unsigned short* R   = Ab  + (long)BATCH * TQ * LKEYS;
    unsigned short* Kb  = R;                                   // 8*2048*256
    unsigned short* Qb  = Kb + (long)BATCH * LKEYS * DP;       // 8*512*256
    float*          S   = (float*)(Qb + (long)BATCH * TQ * DP);// 8*512*2048 f32
    unsigned short* HbT = R;   // [B,Dh,L] bf16, written after S is dead

    transpose_w<<<dim3(DH / 32, DP / 32), 256, 0, stream>>>(Wk, WkT, DH, DP);
    transpose_w<<<dim3(DG / 32, DP / 32), 256, 0, stream>>>(Wq, WqT, DG, DP);

    // K = H @ Wk : M=16384, N=256, K=1024 (A fp32, out bf16). 512 blocks.
    mfma_gemm<128, 64, 0, 1><<<dim3(DP / 64, (BATCH * LKEYS) / 128, 1), 256, 0, stream>>>(
        H, WkT, nullptr, Kb, DH, DH, DH, DP, 0, 0, 0, 0, 1.f);

    // Q = G @ Wq : M=4096, N=256, K=768 (A fp32, out bf16). 256 blocks.
    mfma_gemm<64, 64, 0, 1><<<dim3(DP / 64, (BATCH * TQ) / 64, 1), 256, 0, stream>>>(
        G, WqT, nullptr, Qb, DG, DG, DG, DP, 0, 0, 0, 0, 1.f);

    // logits = scale * Q @ K^T, masked : per batch M=512, N=2048, K=256. 1024 blocks.
    mfma_gemm<128, 64, 1, 2><<<dim3(LKEYS / 64, TQ / 128, BATCH), 256, 0, stream>>>(
        Qb, Kb, mask, S, DP, DP, DP, LKEYS,
        (long)TQ * DP, (long)LKEYS * DP, (long)TQ * LKEYS, (long)LKEYS, SCALE);

    // softmax over L -> bf16 alpha
    softmax_kernel<<<BATCH * TQ, 256, 0, stream>>>(S, Ab);

    // H^T prep (S/Kb/Qb now dead; HbT overlays them)
    prep_HT<<<dim3(DH / 32, LKEYS / 32, BATCH), 256, 0, stream>>>(H, HbT);

    // Z = alpha @ H : per batch M=512, N=1024, K=2048 (out fp32). 512 blocks.
    mfma_gemm<128, 64, 1, 0><<<dim3(DH / 64, TQ / 128, BATCH), 256, 0, stream>>>(
        Ab, HbT, nullptr, Z, LKEYS, LKEYS, LKEYS, DH,
        (long)TQ * LKEYS, (long)DH * LKEYS, (long)TQ * DH, 0, 1.f);
}

// Round 5
// 126.380 us; speedup vs baseline: 4.4684x; 1.2077x over previous
//
#include <hip/hip_runtime.h>
#include <math.h>

// Problem constants: B=8, L=2048, T=512, Dh=1024, Dg=768, Dp=256, SCALE=Dp^-0.5
#define BATCH 8
#define LKEYS 2048
#define TQ    512
#define DH    1024
#define DG    768
#define DP    256
#define SCALE 0.0625f

typedef short  short8  __attribute__((ext_vector_type(8)));   // MFMA A/B frag (8 bf16)
typedef float  floatx4 __attribute__((ext_vector_type(4)));   // MFMA C/D frag
typedef unsigned short u16x4 __attribute__((ext_vector_type(4)));
typedef unsigned short u16x8 __attribute__((ext_vector_type(8)));

typedef unsigned int __attribute__((address_space(1))) as1_uint;
typedef unsigned int __attribute__((address_space(3))) as3_uint;

__device__ __forceinline__ unsigned short f2b(float f) {
    union { float f; unsigned int u; } v; v.f = f;
    unsigned int u = v.u;
    unsigned int r = u + 0x7fffu + ((u >> 16) & 1u);   // RNE
    if ((u & 0x7f800000u) == 0x7f800000u) r = u;        // inf/nan passthrough
    return (unsigned short)(r >> 16);
}

// async global->LDS, 16B per lane (lane-linear LDS dest).
__device__ __forceinline__ void gload_lds16(const void* g, void* l) {
    __builtin_amdgcn_global_load_lds((const as1_uint*)g, (as3_uint*)l, 16, 0, 0);
}

// s_waitcnt immediate: vmcnt=vm, expcnt=max, lgkmcnt=max
__host__ __device__ constexpr int wcnt_vm(int vm) {
    return (vm & 15) | ((vm >> 4) << 14) | (7 << 4) | (15 << 8);
}

// ---------------------------------------------------------------------------
// Pipelined all-bf16 MFMA GEMM (T3/T4): BM x BN tile, 4 waves (2x2),
// BK=32, FOUR LDS buffers, prefetch depth 2, counted vmcnt (no drain-to-0
// in main loop), raw s_barrier (one per iter), setprio around MFMA (T5).
//   OMODE: 0 = C fp32, 1 = C bf16, 2 = C fp32 with scale + key-mask epilogue
//   SWZ:   1 = XCD-chunked blockIdx swizzle (requires gx*gy % 8 == 0)
// A row-major bf16 [M][lda]; B N-major bf16 [N][ldb] (row n = B^T[n][:]).
// Race notes: one barrier/iter bounds wave skew <1 iter; stage writes buf
// (t+3)&3 while possible readers are on t&3 or (t+1)&3 (distance >=2).
// Per-wave counted vmcnt before the barrier => all waves' tile-t loads
// landed once everyone passes the barrier (m201 pattern).
// ---------------------------------------------------------------------------
template<int BM, int BN, int OMODE, int SWZ>
__global__ __launch_bounds__(256) void gemm_bf16_p(
    const unsigned short* __restrict__ Ap, const unsigned short* __restrict__ Bp,
    const int* __restrict__ maskp, void* __restrict__ Cp,
    int K, int lda, int ldb, int ldc,
    long sA, long sB, long sC, long sM, float scale)
{
    constexpr int FM = BM / 32, FN = BN / 32;
    constexpr int AI = BM / 64, BI = BN / 64;
    constexpr int NL = AI + BI;                 // gload_lds per tile per thread

    __shared__ unsigned short As[4][BM * 32];
    __shared__ unsigned short Bs[4][BN * 32];

    int bx = blockIdx.x, by = blockIdx.y;
    if (SWZ) {
        const int gx = gridDim.x;
        const int nwg = gx * gridDim.y;         // must be % 8 == 0
        const int f = by * gx + bx;
        const int nper = nwg >> 3;
        const int fl = (f & 7) * nper + (f >> 3);   // chunk per XCD
        bx = fl % gx; by = fl / gx;
    }
    const int z    = blockIdx.z;
    const int tid  = threadIdx.x;
    const int lane = tid & 63;
    const int wid  = tid >> 6;
    const int wr   = wid >> 1, wc = wid & 1;
    const int lrow = lane & 15;
    const int g    = lane >> 4;

    const unsigned short* A = Ap + (long)z * sA + (long)(by * BM) * lda;
    const unsigned short* B = Bp + (long)z * sB + (long)(bx * BN) * ldb;
    const int srow = tid >> 2, sslot = tid & 3;

    const int nt = K / 32;
    floatx4 acc[FM][FN] = {};

    auto stage = [&](int t, int b) {
        const int k0 = t * 32;
        #pragma unroll
        for (int i = 0; i < AI; ++i)
            gload_lds16(A + (long)(srow + i * 64) * lda + k0 + sslot * 8,
                        (void*)&As[b][(i * 256 + tid) * 8]);
        #pragma unroll
        for (int i = 0; i < BI; ++i)
            gload_lds16(B + (long)(srow + i * 64) * ldb + k0 + sslot * 8,
                        (void*)&Bs[b][(i * 256 + tid) * 8]);
    };

    stage(0, 0);
    stage(1, 1);
    for (int t = 0; t < nt; ++t) {
        if (t + 2 < nt) {
            stage(t + 2, (t + 2) & 3);
            __builtin_amdgcn_s_waitcnt(wcnt_vm(2 * NL));   // tile t landed (mine)
        } else if (t + 1 < nt) {
            __builtin_amdgcn_s_waitcnt(wcnt_vm(NL));
        } else {
            __builtin_amdgcn_s_waitcnt(wcnt_vm(0));
        }
        __builtin_amdgcn_s_barrier();                      // everyone's tile t landed
        __builtin_amdgcn_sched_barrier(0);

        const int b = t & 3;
        short8 a[FM], bf[FN];
        #pragma unroll
        for (int m = 0; m < FM; ++m)
            a[m] = *(const short8*)&As[b][(wr * (BM / 2) + m * 16 + lrow) * 32 + g * 8];
        #pragma unroll
        for (int n = 0; n < FN; ++n)
            bf[n] = *(const short8*)&Bs[b][(wc * (BN / 2) + n * 16 + lrow) * 32 + g * 8];
        __builtin_amdgcn_s_setprio(1);
        #pragma unroll
        for (int m = 0; m < FM; ++m)
            #pragma unroll
            for (int n = 0; n < FN; ++n)
                acc[m][n] = __builtin_amdgcn_mfma_f32_16x16x32_bf16(
                    a[m], bf[n], acc[m][n], 0, 0, 0);
        __builtin_amdgcn_s_setprio(0);
        __builtin_amdgcn_sched_barrier(0);                 // keep phase intact
    }

    // ---- epilogue: D row = 4g + reg, col = lrow (m89-verified layout) ----
    const int orow = by * BM + wr * (BM / 2);
    const int ocol = bx * BN + wc * (BN / 2);
    if (OMODE == 0) {
        float* C = (float*)Cp + (long)z * sC;
        #pragma unroll
        for (int m = 0; m < FM; ++m)
            #pragma unroll
            for (int n = 0; n < FN; ++n)
                #pragma unroll
                for (int r = 0; r < 4; ++r)
                    C[(long)(orow + m * 16 + 4 * g + r) * ldc + ocol + n * 16 + lrow]
                        = acc[m][n][r];
    } else if (OMODE == 1) {
        unsigned short* C = (unsigned short*)Cp + (long)z * sC;
        #pragma unroll
        for (int m = 0; m < FM; ++m)
            #pragma unroll
            for (int n = 0; n < FN; ++n)
                #pragma unroll
                for (int r = 0; r < 4; ++r)
                    C[(long)(orow + m * 16 + 4 * g + r) * ldc + ocol + n * 16 + lrow]
                        = f2b(acc[m][n][r]);
    } else {
        const int* mask = maskp + (long)z * sM;
        float* C = (float*)Cp + (long)z * sC;
        #pragma unroll
        for (int n = 0; n < FN; ++n) {
            int c = ocol + n * 16 + lrow;
            bool masked = (mask[c] != 0);
            #pragma unroll
            for (int m = 0; m < FM; ++m)
                #pragma unroll
                for (int r = 0; r < 4; ++r)
                    C[(long)(orow + m * 16 + 4 * g + r) * ldc + c]
                        = masked ? -INFINITY : acc[m][n][r] * scale;
        }
    }
}

// ---------------------------------------------------------------------------
// Legacy fp32-A GEMM (plan-B fallback only): R4 structure, double-buffered
// __syncthreads loop, reg-stage+convert A, gload_lds B. + XCD swizzle.
// ---------------------------------------------------------------------------
template<int BM, int BN, int OMODE, int SWZ>
__global__ __launch_bounds__(256) void gemm_f32a(
    const float* __restrict__ Ap, const unsigned short* __restrict__ Bp,
    void* __restrict__ Cp, int K, int lda, int ldb, int ldc)
{
    constexpr int FM = BM / 32, FN = BN / 32;
    constexpr int AI = BM / 64, BI = BN / 64;

    __shared__ unsigned short As[2][BM * 32];
    __shared__ unsigned short Bs[2][BN * 32];

    int bx = blockIdx.x, by = blockIdx.y;
    if (SWZ) {
        const int gx = gridDim.x;
        const int nwg = gx * gridDim.y;
        const int f = by * gx + bx;
        const int nper = nwg >> 3;
        const int fl = (f & 7) * nper + (f >> 3);
        bx = fl % gx; by = fl / gx;
    }
    const int tid  = threadIdx.x;
    const int lane = tid & 63;
    const int wid  = tid >> 6;
    const int wr   = wid >> 1, wc = wid & 1;
    const int lrow = lane & 15;
    const int g    = lane >> 4;

    const float* A = Ap + (long)(by * BM) * lda;
    const unsigned short* B = Bp + (long)(bx * BN) * ldb;
    const int srow = tid >> 2, sslot = tid & 3;

    floatx4 acc[FM][FN] = {};
    const int nt = K / 32;
    int cur = 0;

    {
        float4 pa[AI][2];
        #pragma unroll
        for (int i = 0; i < AI; ++i) {
            const float* p = A + (long)(srow + i * 64) * lda + sslot * 8;
            pa[i][0] = *(const float4*)p;
            pa[i][1] = *(const float4*)(p + 4);
        }
        #pragma unroll
        for (int i = 0; i < BI; ++i)
            gload_lds16(B + (long)(srow + i * 64) * ldb + sslot * 8,
                        (void*)&Bs[0][(i * 256 + tid) * 8]);
        #pragma unroll
        for (int i = 0; i < AI; ++i) {
            u16x8 w;
            w[0] = f2b(pa[i][0].x); w[1] = f2b(pa[i][0].y);
            w[2] = f2b(pa[i][0].z); w[3] = f2b(pa[i][0].w);
            w[4] = f2b(pa[i][1].x); w[5] = f2b(pa[i][1].y);
            w[6] = f2b(pa[i][1].z); w[7] = f2b(pa[i][1].w);
            *(u16x8*)&As[0][(i * 256 + tid) * 8] = w;
        }
    }
    __syncthreads();

    for (int t = 0; t < nt; ++t) {
        float4 pa[AI][2];
        const bool pf = (t + 1 < nt);
        if (pf) {
            int k0 = (t + 1) * 32;
            #pragma unroll
            for (int i = 0; i < AI; ++i) {
                const float* p = A + (long)(srow + i * 64) * lda + k0 + sslot * 8;
                pa[i][0] = *(const float4*)p;
                pa[i][1] = *(const float4*)(p + 4);
            }
            #pragma unroll
            for (int i = 0; i < BI; ++i)
                gload_lds16(B + (long)(srow + i * 64) * ldb + k0 + sslot * 8,
                            (void*)&Bs[cur ^ 1][(i * 256 + tid) * 8]);
        }
        short8 a[FM], bf[FN];
        #pragma unroll
        for (int m = 0; m < FM; ++m)
            a[m] = *(const short8*)&As[cur][(wr * (BM / 2) + m * 16 + lrow) * 32 + g * 8];
        #pragma unroll
        for (int n = 0; n < FN; ++n)
            bf[n] = *(const short8*)&Bs[cur][(wc * (BN / 2) + n * 16 + lrow) * 32 + g * 8];
        #pragma unroll
        for (int m = 0; m < FM; ++m)
            #pragma unroll
            for (int n = 0; n < FN; ++n)
                acc[m][n] = __builtin_amdgcn_mfma_f32_16x16x32_bf16(
                    a[m], bf[n], acc[m][n], 0, 0, 0);
        if (pf) {
            #pragma unroll
            for (int i = 0; i < AI; ++i) {
                u16x8 w;
                w[0] = f2b(pa[i][0].x); w[1] = f2b(pa[i][0].y);
                w[2] = f2b(pa[i][0].z); w[3] = f2b(pa[i][0].w);
                w[4] = f2b(pa[i][1].x); w[5] = f2b(pa[i][1].y);
                w[6] = f2b(pa[i][1].z); w[7] = f2b(pa[i][1].w);
                *(u16x8*)&As[cur ^ 1][(i * 256 + tid) * 8] = w;
            }
        }
        __syncthreads();
        cur ^= 1;
    }

    const int orow = by * BM + wr * (BM / 2);
    const int ocol = bx * BN + wc * (BN / 2);
    if (OMODE == 1) {
        unsigned short* C = (unsigned short*)Cp;
        #pragma unroll
        for (int m = 0; m < FM; ++m)
            #pragma unroll
            for (int n = 0; n < FN; ++n)
                #pragma unroll
                for (int r = 0; r < 4; ++r)
                    C[(long)(orow + m * 16 + 4 * g + r) * ldc + ocol + n * 16 + lrow]
                        = f2b(acc[m][n][r]);
    } else {
        float* C = (float*)Cp;
        #pragma unroll
        for (int m = 0; m < FM; ++m)
            #pragma unroll
            for (int n = 0; n < FN; ++n)
                #pragma unroll
                for (int r = 0; r < 4; ++r)
                    C[(long)(orow + m * 16 + 4 * g + r) * ldc + ocol + n * 16 + lrow]
                        = acc[m][n][r];
    }
}

// ---------------------------------------------------------------------------
// Weight transpose + convert: W [D][P] fp32 -> WT [P][D] bf16.
// ---------------------------------------------------------------------------
__global__ __launch_bounds__(256) void transpose_w(
    const float* __restrict__ W, unsigned short* __restrict__ WT, int D, int P)
{
    __shared__ float t[32][33];
    const int d0 = blockIdx.x * 32, p0 = blockIdx.y * 32;
    const int tx = threadIdx.x & 31, ty = threadIdx.x >> 5;   // 32x8
    #pragma unroll
    for (int j = 0; j < 4; ++j)
        t[ty + 8 * j][tx] = W[(long)(d0 + ty + 8 * j) * P + p0 + tx];
    __syncthreads();
    #pragma unroll
    for (int j = 0; j < 4; ++j)
        WT[(long)(p0 + ty + 8 * j) * D + d0 + tx] = f2b(t[tx][ty + 8 * j]);
}

// ---------------------------------------------------------------------------
// Plan A: H [B,L,Dh] fp32 -> Hb [B,L,Dh] bf16 AND HbT [B,Dh,L] bf16, one read.
// ---------------------------------------------------------------------------
__global__ __launch_bounds__(256) void prep_H(
    const float* __restrict__ H, unsigned short* __restrict__ Hb,
    unsigned short* __restrict__ HbT)
{
    __shared__ float tf[32][33];
    const int z = blockIdx.z;
    const int d0 = blockIdx.x * 32, l0 = blockIdx.y * 32;
    const float* Hz = H + (long)z * LKEYS * DH;
    unsigned short* Hbz = Hb + (long)z * LKEYS * DH;
    unsigned short* Tz = HbT + (long)z * DH * LKEYS;
    const int r = threadIdx.x >> 3, c = threadIdx.x & 7;
    float4 v = *(const float4*)&Hz[(long)(l0 + r) * DH + d0 + 4 * c];
    u16x4 w;
    w[0] = f2b(v.x); w[1] = f2b(v.y); w[2] = f2b(v.z); w[3] = f2b(v.w);
    *(u16x4*)&Hbz[(long)(l0 + r) * DH + d0 + 4 * c] = w;
    tf[r][4 * c + 0] = v.x; tf[r][4 * c + 1] = v.y;
    tf[r][4 * c + 2] = v.z; tf[r][4 * c + 3] = v.w;
    __syncthreads();
    u16x4 o;
    o[0] = f2b(tf[4 * c + 0][r]); o[1] = f2b(tf[4 * c + 1][r]);
    o[2] = f2b(tf[4 * c + 2][r]); o[3] = f2b(tf[4 * c + 3][r]);
    *(u16x4*)&Tz[(long)(d0 + r) * LKEYS + l0 + 4 * c] = o;
}

// Plan B: H -> HbT only (R4 behavior).
__global__ __launch_bounds__(256) void prep_HT(
    const float* __restrict__ H, unsigned short* __restrict__ HbT)
{
    __shared__ float tf[32][33];
    const int z = blockIdx.z;
    const int d0 = blockIdx.x * 32, l0 = blockIdx.y * 32;
    const float* Hz = H + (long)z * LKEYS * DH;
    unsigned short* Tz = HbT + (long)z * DH * LKEYS;
    const int r = threadIdx.x >> 3, c = threadIdx.x & 7;
    float4 v = *(const float4*)&Hz[(long)(l0 + r) * DH + d0 + 4 * c];
    tf[r][4 * c + 0] = v.x; tf[r][4 * c + 1] = v.y;
    tf[r][4 * c + 2] = v.z; tf[r][4 * c + 3] = v.w;
    __syncthreads();
    u16x4 o;
    o[0] = f2b(tf[4 * c + 0][r]); o[1] = f2b(tf[4 * c + 1][r]);
    o[2] = f2b(tf[4 * c + 2][r]); o[3] = f2b(tf[4 * c + 3][r]);
    *(u16x4*)&Tz[(long)(d0 + r) * LKEYS + l0 + 4 * c] = o;
}

// G fp32 -> Gb bf16, streaming (8 elems/thread, exact grid).
__global__ __launch_bounds__(256) void prep_G(
    const float* __restrict__ G, unsigned short* __restrict__ Gb)
{
    long i = ((long)blockIdx.x * 256 + threadIdx.x) * 8;
    float4 a = *(const float4*)&G[i];
    float4 b = *(const float4*)&G[i + 4];
    u16x8 w;
    w[0] = f2b(a.x); w[1] = f2b(a.y); w[2] = f2b(a.z); w[3] = f2b(a.w);
    w[4] = f2b(b.x); w[5] = f2b(b.y); w[6] = f2b(b.z); w[7] = f2b(b.w);
    *(u16x8*)&Gb[i] = w;
}

// ---------------------------------------------------------------------------
// Row softmax, register-cached: 2048 floats/row, 256 threads, 8 elems/thread.
// ---------------------------------------------------------------------------
__global__ __launch_bounds__(256) void softmax_kernel(
    const float* __restrict__ S, unsigned short* __restrict__ Ab)
{
    const float4* row4 = (const float4*)(S + (long)blockIdx.x * LKEYS);
    u16x4* out4 = (u16x4*)(Ab + (long)blockIdx.x * LKEYS);
    const int tid = threadIdx.x;
    __shared__ float red[4];

    float4 v0 = row4[tid], v1 = row4[tid + 256];
    float m = fmaxf(fmaxf(fmaxf(v0.x, v0.y), fmaxf(v0.z, v0.w)),
                    fmaxf(fmaxf(v1.x, v1.y), fmaxf(v1.z, v1.w)));
    #pragma unroll
    for (int off = 32; off > 0; off >>= 1) m = fmaxf(m, __shfl_xor(m, off));
    if ((tid & 63) == 0) red[tid >> 6] = m;
    __syncthreads();
    m = fmaxf(fmaxf(red[0], red[1]), fmaxf(red[2], red[3]));

    float e[8];
    e[0] = __expf(v0.x - m); e[1] = __expf(v0.y - m);
    e[2] = __expf(v0.z - m); e[3] = __expf(v0.w - m);
    e[4] = __expf(v1.x - m); e[5] = __expf(v1.y - m);
    e[6] = __expf(v1.z - m); e[7] = __expf(v1.w - m);
    float s = ((e[0] + e[1]) + (e[2] + e[3])) + ((e[4] + e[5]) + (e[6] + e[7]));
    #pragma unroll
    for (int off = 32; off > 0; off >>= 1) s += __shfl_xor(s, off);
    __syncthreads();
    if ((tid & 63) == 0) red[tid >> 6] = s;
    __syncthreads();
    s = red[0] + red[1] + red[2] + red[3];

    float inv = 1.0f / s;
    u16x4 a0, a1;
    a0[0] = f2b(e[0] * inv); a0[1] = f2b(e[1] * inv);
    a0[2] = f2b(e[2] * inv); a0[3] = f2b(e[3] * inv);
    a1[0] = f2b(e[4] * inv); a1[1] = f2b(e[5] * inv);
    a1[2] = f2b(e[6] * inv); a1[3] = f2b(e[7] * inv);
    out4[tid] = a0; out4[tid + 256] = a1;
}

// ---------------------------------------------------------------------------
extern "C" void kernel_launch(void* const* d_in, const int* in_sizes, int n_in,
                              void* d_out, int out_size, void* d_ws, size_t ws_size,
                              hipStream_t stream)
{
    const float* H    = (const float*)d_in[0];  // [B,L,Dh]
    const float* G    = (const float*)d_in[1];  // [B,T,Dg]
    const int*   mask = (const int*)  d_in[2];  // [B,L]
    const float* Wk   = (const float*)d_in[3];  // [Dh,Dp]
    const float* Wq   = (const float*)d_in[4];  // [Dg,Dp]
    float*       Z    = (float*)d_out;          // [B,T,Dh]

    unsigned short* WkT = (unsigned short*)d_ws;      // 256*1024
    unsigned short* WqT = WkT + 262144;               // 256*768
    unsigned short* Ab  = WqT + 196608;               // 8*512*2048 bf16

    transpose_w<<<dim3(DH / 32, DP / 32), 256, 0, stream>>>(Wk, WkT, DH, DP);
    transpose_w<<<dim3(DG / 32, DP / 32), 256, 0, stream>>>(Wq, WqT, DG, DP);

    const size_t NEED_A = 101580800ull;  // plan-A workspace bytes

    if (ws_size >= NEED_A) {
        // Plan A: all-bf16 GEMMs. Layout (u16 units):
        // WkT|WqT|Ab|Kb|Qb|Gb|HbT|HbS(Hb then S; Hb dead before S is born)
        unsigned short* Kb  = Ab  + 8388608;   // 8*2048*256
        unsigned short* Qb  = Kb  + 4194304;   // 8*512*256
        unsigned short* Gb  = Qb  + 1048576;   // 8*512*768
        unsigned short* HbT = Gb  + 3145728;   // 8*1024*2048
        unsigned short* Hb  = HbT + 16777216;  // 8*2048*1024
        float*          S   = (float*)Hb;      // overlays Hb

        prep_G<<<1536, 256, 0, stream>>>(G, Gb);
        prep_H<<<dim3(DH / 32, LKEYS / 32, BATCH), 256, 0, stream>>>(H, Hb, HbT);

        // K = Hb @ WkT^T : M=16384, N=256, K=1024 -> Kb bf16. 512 blocks, swz.
        gemm_bf16_p<128, 64, 1, 1><<<dim3(4, 128, 1), 256, 0, stream>>>(
            Hb, WkT, nullptr, Kb, DH, DH, DH, DP, 0, 0, 0, 0, 1.f);

        // Q = Gb @ WqT^T : M=4096, N=256, K=768 -> Qb bf16. 256 blocks, swz.
        gemm_bf16_p<64, 64, 1, 1><<<dim3(4, 64, 1), 256, 0, stream>>>(
            Gb, WqT, nullptr, Qb, DG, DG, DG, DP, 0, 0, 0, 0, 1.f);

        // logits = scale * Qb @ Kb^T, masked : per batch 512x2048x256 -> S fp32.
        gemm_bf16_p<128, 64, 2, 0><<<dim3(32, 4, BATCH), 256, 0, stream>>>(
            Qb, Kb, mask, S, DP, DP, DP, LKEYS,
            (long)TQ * DP, (long)LKEYS * DP, (long)TQ * LKEYS, (long)LKEYS, SCALE);

        softmax_kernel<<<BATCH * TQ, 256, 0, stream>>>(S, Ab);

        // Z = Ab @ HbT^T : per batch 512x1024x2048 -> Z fp32. 512 blocks, swz.
        gemm_bf16_p<128, 64, 0, 1><<<dim3(16, 4, BATCH), 256, 0, stream>>>(
            Ab, HbT, nullptr, Z, LKEYS, LKEYS, LKEYS, DH,
            (long)TQ * LKEYS, (long)DH * LKEYS, (long)TQ * DH, 0, 1.f);
    } else {
        // Plan B (R4 fallback, 61.7 MB): WkT|WqT|Ab|region[Kb|Qb|S], HbT overlays region
        unsigned short* R   = Ab + 8388608;
        unsigned short* Kb  = R;
        unsigned short* Qb  = Kb + 4194304;
        float*          S   = (float*)(Qb + 1048576);
        unsigned short* HbT = R;

        gemm_f32a<128, 64, 1, 1><<<dim3(4, 128, 1), 256, 0, stream>>>(
            H, WkT, Kb, DH, DH, DH, DP);
        gemm_f32a<64, 64, 1, 1><<<dim3(4, 64, 1), 256, 0, stream>>>(
            G, WqT, Qb, DG, DG, DG, DP);

        gemm_bf16_p<128, 64, 2, 0><<<dim3(32, 4, BATCH), 256, 0, stream>>>(
            Qb, Kb, mask, S, DP, DP, DP, LKEYS,
            (long)TQ * DP, (long)LKEYS * DP, (long)TQ * LKEYS, (long)LKEYS, SCALE);

        softmax_kernel<<<BATCH * TQ, 256, 0, stream>>>(S, Ab);

        prep_HT<<<dim3(DH / 32, LKEYS / 32, BATCH), 256, 0, stream>>>(H, HbT);

        gemm_bf16_p<128, 64, 0, 1><<<dim3(16, 4, BATCH), 256, 0, stream>>>(
            Ab, HbT, nullptr, Z, LKEYS, LKEYS, LKEYS, DH,
            (long)TQ * LKEYS, (long)DH * LKEYS, (long)TQ * DH, 0, 1.f);
    }
}